// Round 5
// baseline (360.934 us; speedup 1.0000x reference)
//
#include <hip/hip_runtime.h>
#include <stdint.h>

typedef unsigned short ushort_t;
typedef __bf16 bf16x8 __attribute__((ext_vector_type(8)));
typedef float f32x4 __attribute__((ext_vector_type(4)));
typedef unsigned short ushort8 __attribute__((ext_vector_type(8)));
typedef unsigned short ushort4_t __attribute__((ext_vector_type(4)));
typedef __attribute__((address_space(1))) void GVoid;
typedef __attribute__((address_space(3))) void LVoid;

#define DEV static __device__ __forceinline__

DEV unsigned short f2bf(float f) {
    union { float f; unsigned int i; } v; v.f = f;
    unsigned int u = v.i;
    return (unsigned short)((u + 0x7fffu + ((u >> 16) & 1u)) >> 16);
}
DEV float bf2f(unsigned short u) {
    union { unsigned int i; float f; } v; v.i = ((unsigned int)u) << 16; return v.f;
}

// ---------------------------------------------------------------------------
// fp32 -> bf16 conversion, 1 elem/thread (weights, small)
// ---------------------------------------------------------------------------
__global__ __launch_bounds__(256) void cvt_kernel(
    const float* __restrict__ in, ushort_t* __restrict__ out, int n)
{
    int i = blockIdx.x * 256 + threadIdx.x;
    if (i < n) out[i] = f2bf(in[i]);
}

// fp32 -> bf16, 4 elems/thread (points2, 4.19M elems)
__global__ __launch_bounds__(256) void cvt4_kernel(
    const float* __restrict__ in, ushort_t* __restrict__ out)
{
    int i = (blockIdx.x * 256 + threadIdx.x) * 4;
    float4 v = *(const float4*)(in + i);
    ushort4_t o;
    o[0] = f2bf(v.x); o[1] = f2bf(v.y); o[2] = f2bf(v.z); o[3] = f2bf(v.w);
    *(ushort4_t*)(out + i) = o;
}

// ---------------------------------------------------------------------------
// 3-NN v3: 8-way candidate split. Block = 32 queries x 8 chunks of 128.
// Chunk-ascending merge + strict < insertion == stable lax.top_k ordering.
// Grid 2048 blocks -> ~32 waves/CU available.
// ---------------------------------------------------------------------------
__global__ __launch_bounds__(256) void knn_kernel(
    const float* __restrict__ xyz1, const float* __restrict__ xyz2,
    int* __restrict__ idx_out, float* __restrict__ w_out)
{
    __shared__ float4 P[1024];
    __shared__ float mD[24][32];
    __shared__ int   mI[24][32];
    const int b = blockIdx.y;
    const int tid = threadIdx.x;
    for (int s = tid; s < 1024; s += 256) {
        const float* p = xyz2 + ((size_t)b * 1024 + s) * 3;
        float x = p[0], y = p[1], z = p[2];
        float pp = __fadd_rn(__fadd_rn(__fmul_rn(x, x), __fmul_rn(y, y)), __fmul_rn(z, z));
        P[s] = make_float4(x, y, z, pp);
    }
    __syncthreads();
    const int ql = tid & 31;
    const int chunk = tid >> 5;
    const int n = blockIdx.x * 32 + ql;
    const float* q = xyz1 + ((size_t)b * 4096 + n) * 3;
    float qx = q[0], qy = q[1], qz = q[2];
    float qq = __fadd_rn(__fadd_rn(__fmul_rn(qx, qx), __fmul_rn(qy, qy)), __fmul_rn(qz, qz));
    float d0 = 1e30f, d1 = 1e30f, d2 = 1e30f;
    int i0 = 0, i1 = 0, i2 = 0;
    const int s0 = chunk * 128;
#pragma unroll 4
    for (int s = s0; s < s0 + 128; ++s) {
        float4 p = P[s];
        float dot = __fadd_rn(__fadd_rn(__fmul_rn(qx, p.x), __fmul_rn(qy, p.y)), __fmul_rn(qz, p.z));
        float d = __fsub_rn(__fadd_rn(qq, p.w), __fmul_rn(2.0f, dot));
        if (d < d2) {
            if (d < d1) {
                d2 = d1; i2 = i1;
                if (d < d0) { d1 = d0; i1 = i0; d0 = d; i0 = s; }
                else        { d1 = d;  i1 = s; }
            } else { d2 = d; i2 = s; }
        }
    }
    mD[chunk * 3 + 0][ql] = d0; mI[chunk * 3 + 0][ql] = i0;
    mD[chunk * 3 + 1][ql] = d1; mI[chunk * 3 + 1][ql] = i1;
    mD[chunk * 3 + 2][ql] = d2; mI[chunk * 3 + 2][ql] = i2;
    __syncthreads();
    if (tid < 32) {
        float e0 = 1e30f, e1 = 1e30f, e2 = 1e30f;
        int j0 = 0, j1 = 0, j2 = 0;
#pragma unroll
        for (int c = 0; c < 24; ++c) {
            float d = mD[c][ql]; int i = mI[c][ql];
            if (d < e2) {
                if (d < e1) {
                    e2 = e1; j2 = j1;
                    if (d < e0) { e1 = e0; j1 = j0; e0 = d; j0 = i; }
                    else        { e1 = d;  j1 = i; }
                } else { e2 = d; j2 = i; }
            }
        }
        float r0 = 1.0f / (e0 + 1e-8f);
        float r1 = 1.0f / (e1 + 1e-8f);
        float r2 = 1.0f / (e2 + 1e-8f);
        float rs = __fadd_rn(__fadd_rn(r0, r1), r2);
        size_t o = ((size_t)b * 4096 + n) * 3;
        idx_out[o + 0] = j0; idx_out[o + 1] = j1; idx_out[o + 2] = j2;
        w_out[o + 0] = r0 / rs; w_out[o + 1] = r1 / rs; w_out[o + 2] = r2 / rs;
    }
}

// ---------------------------------------------------------------------------
// Interp: itp[q, 0:256] = sum_k w_k * p2b[idx_k]. One thread = (query, 32-ch
// group); gathers from bf16 points2 (8.4 MB, L2/L3-resident). Grid 2048.
// ---------------------------------------------------------------------------
__global__ __launch_bounds__(256) void interp_kernel(
    const ushort_t* __restrict__ p2b, const int* __restrict__ idx,
    const float* __restrict__ wgt, ushort_t* __restrict__ itp)
{
    const int t = blockIdx.x * 256 + threadIdx.x;
    const int q = t >> 3;
    const int cg = (t & 7) * 32;
    const size_t o = (size_t)q * 3;
    int i0 = idx[o], i1 = idx[o + 1], i2 = idx[o + 2];
    float w0 = wgt[o], w1 = wgt[o + 1], w2 = wgt[o + 2];
    const ushort_t* pb = p2b + (size_t)(q >> 12) * (1024 * 256);
    const ushort8* g0 = (const ushort8*)(pb + (size_t)i0 * 256 + cg);
    const ushort8* g1 = (const ushort8*)(pb + (size_t)i1 * 256 + cg);
    const ushort8* g2 = (const ushort8*)(pb + (size_t)i2 * 256 + cg);
    ushort8* dst = (ushort8*)(itp + (size_t)q * 256 + cg);
#pragma unroll
    for (int s = 0; s < 4; ++s) {
        ushort8 a = g0[s], b = g1[s], c = g2[s];
        ushort8 ov;
#pragma unroll
        for (int j = 0; j < 8; ++j) {
            float acc = __fmul_rn(w0, bf2f(a[j]));
            acc = fmaf(w1, bf2f(b[j]), acc);
            acc = fmaf(w2, bf2f(c[j]), acc);
            ov[j] = f2bf(acc);
        }
        dst[s] = ov;
    }
}

DEV void cvt8(const float4& u0, const float4& u1, ushort8& hv) {
    hv[0] = f2bf(u0.x); hv[1] = f2bf(u0.y); hv[2] = f2bf(u0.z); hv[3] = f2bf(u0.w);
    hv[4] = f2bf(u1.x); hv[5] = f2bf(u1.y); hv[6] = f2bf(u1.z); hv[7] = f2bf(u1.w);
}

// ---------------------------------------------------------------------------
// GEMM1 v3: pure streaming GEMM. y1 = [p1(fp32,cvt) | itp(bf16)] @ w1b^T.
// BM=32, BN=256, BK=32, grid 2048, LDS 18.5 KB (~5 blocks/CU).
// As padded to 40 elem/row: frag read dword = 4*((5*frl+fq)%8) -> conflict-
// free b128. B via global_load_lds width=16 (m97 pattern). Stats fused.
// ---------------------------------------------------------------------------
__global__ __launch_bounds__(256) void gemm1_kernel(
    const float* __restrict__ p1, const ushort_t* __restrict__ itp,
    const ushort_t* __restrict__ w1b, ushort_t* __restrict__ y,
    float* __restrict__ sums, float* __restrict__ sqs)
{
    __shared__ __align__(16) ushort_t As[32 * 40];   // 2.5 KB padded
    __shared__ __align__(16) ushort_t Bs[256 * 32];  // 16 KB
    const int tid = threadIdx.x;
    const int wave = tid >> 6, lane = tid & 63;
    const int frl = lane & 15, fq = lane >> 4;
    const int m0 = blockIdx.x * 32;
    const int sr = tid >> 2, sq = tid & 3;

    f32x4 acc[2][4];
#pragma unroll
    for (int i = 0; i < 2; ++i)
#pragma unroll
        for (int j = 0; j < 4; ++j) acc[i][j] = f32x4{0.0f, 0.0f, 0.0f, 0.0f};

    for (int kc = 0; kc < 16; ++kc) {
        __syncthreads();
#pragma unroll
        for (int p = 0; p < 4; ++p) {
            const ushort_t* g = w1b + (size_t)(p * 64 + sr) * 512 + kc * 32 + sq * 8;
            __builtin_amdgcn_global_load_lds((GVoid*)g, (LVoid*)(Bs + p * 2048 + wave * 512), 16, 0, 0);
        }
        if (tid < 128) {
            ushort8 hv;
            if (kc < 8) {
                const float4* g = (const float4*)(p1 + (size_t)(m0 + sr) * 256 + kc * 32 + sq * 8);
                float4 u0 = g[0], u1 = g[1];
                cvt8(u0, u1, hv);
            } else {
                hv = *(const ushort8*)(itp + (size_t)(m0 + sr) * 256 + (kc - 8) * 32 + sq * 8);
            }
            *(ushort8*)(As + sr * 40 + sq * 8) = hv;
        }
        __syncthreads();
        bf16x8 af[2], bfr[4];
#pragma unroll
        for (int i = 0; i < 2; ++i)
            af[i] = *(const bf16x8*)(As + (i * 16 + frl) * 40 + fq * 8);
#pragma unroll
        for (int j = 0; j < 4; ++j)
            bfr[j] = *(const bf16x8*)(Bs + (wave * 64 + j * 16 + frl) * 32 + fq * 8);
#pragma unroll
        for (int i = 0; i < 2; ++i)
#pragma unroll
            for (int j = 0; j < 4; ++j)
                acc[i][j] = __builtin_amdgcn_mfma_f32_16x16x32_bf16(af[i], bfr[j], acc[i][j], 0, 0, 0);
    }

    // epilogue: y1 bf16 store + fused BN1 stats (1 atomic per col per block)
#pragma unroll
    for (int j = 0; j < 4; ++j) {
        const int col = wave * 64 + j * 16 + frl;
        float s = 0.f, q = 0.f;
#pragma unroll
        for (int i = 0; i < 2; ++i)
#pragma unroll
            for (int rr = 0; rr < 4; ++rr) {
                ushort_t hb = f2bf(acc[i][j][rr]);
                float v = bf2f(hb);
                y[(size_t)(m0 + i * 16 + fq * 4 + rr) * 256 + col] = hb;
                s += v; q = fmaf(v, v, q);
            }
        s += __shfl_xor(s, 16); s += __shfl_xor(s, 32);
        q += __shfl_xor(q, 16); q += __shfl_xor(q, 32);
        if (fq == 0) { atomicAdd(&sums[col], s); atomicAdd(&sqs[col], q); }
    }
}

// ---------------------------------------------------------------------------
// GEMM2 v3: out(fp32) = relu(bn1(y1)) @ w2b^T. Same structure, K=256.
// BN folded during A-staging. Stats2 fused.
// ---------------------------------------------------------------------------
__global__ __launch_bounds__(256) void gemm2_kernel(
    const ushort_t* __restrict__ y1, const ushort_t* __restrict__ w2b,
    const float* __restrict__ a1, const float* __restrict__ c1,
    float* __restrict__ y2, float* __restrict__ sums, float* __restrict__ sqs)
{
    __shared__ __align__(16) ushort_t As[32 * 40];
    __shared__ __align__(16) ushort_t Bs[256 * 32];
    __shared__ float sA[256], sC[256];
    const int tid = threadIdx.x;
    const int wave = tid >> 6, lane = tid & 63;
    const int frl = lane & 15, fq = lane >> 4;
    const int m0 = blockIdx.x * 32;
    const int sr = tid >> 2, sq = tid & 3;

    sA[tid] = a1[tid]; sC[tid] = c1[tid];

    f32x4 acc[2][4];
#pragma unroll
    for (int i = 0; i < 2; ++i)
#pragma unroll
        for (int j = 0; j < 4; ++j) acc[i][j] = f32x4{0.0f, 0.0f, 0.0f, 0.0f};

    for (int kc = 0; kc < 8; ++kc) {
        __syncthreads();
#pragma unroll
        for (int p = 0; p < 4; ++p) {
            const ushort_t* g = w2b + (size_t)(p * 64 + sr) * 256 + kc * 32 + sq * 8;
            __builtin_amdgcn_global_load_lds((GVoid*)g, (LVoid*)(Bs + p * 2048 + wave * 512), 16, 0, 0);
        }
        if (tid < 128) {
            ushort8 raw = *(const ushort8*)(y1 + (size_t)(m0 + sr) * 256 + kc * 32 + sq * 8);
            const int ch = kc * 32 + sq * 8;
            ushort8 hv;
#pragma unroll
            for (int j = 0; j < 8; ++j) {
                float v = bf2f(raw[j]);
                hv[j] = f2bf(fmaxf(fmaf(v, sA[ch + j], sC[ch + j]), 0.0f));
            }
            *(ushort8*)(As + sr * 40 + sq * 8) = hv;
        }
        __syncthreads();
        bf16x8 af[2], bfr[4];
#pragma unroll
        for (int i = 0; i < 2; ++i)
            af[i] = *(const bf16x8*)(As + (i * 16 + frl) * 40 + fq * 8);
#pragma unroll
        for (int j = 0; j < 4; ++j)
            bfr[j] = *(const bf16x8*)(Bs + (wave * 64 + j * 16 + frl) * 32 + fq * 8);
#pragma unroll
        for (int i = 0; i < 2; ++i)
#pragma unroll
            for (int j = 0; j < 4; ++j)
                acc[i][j] = __builtin_amdgcn_mfma_f32_16x16x32_bf16(af[i], bfr[j], acc[i][j], 0, 0, 0);
    }

#pragma unroll
    for (int j = 0; j < 4; ++j) {
        const int col = wave * 64 + j * 16 + frl;
        float s = 0.f, q = 0.f;
#pragma unroll
        for (int i = 0; i < 2; ++i)
#pragma unroll
            for (int rr = 0; rr < 4; ++rr) {
                float v = acc[i][j][rr];
                y2[(size_t)(m0 + i * 16 + fq * 4 + rr) * 256 + col] = v;
                s += v; q = fmaf(v, v, q);
            }
        s += __shfl_xor(s, 16); s += __shfl_xor(s, 32);
        q += __shfl_xor(q, 16); q += __shfl_xor(q, 32);
        if (fq == 0) { atomicAdd(&sums[col], s); atomicAdd(&sqs[col], q); }
    }
}

__global__ __launch_bounds__(256) void finalize_kernel(
    const float* __restrict__ sums, const float* __restrict__ sqs,
    const float* __restrict__ g, const float* __restrict__ bias,
    float* __restrict__ a, float* __restrict__ c)
{
    const int ch = threadIdx.x;
    const float inv_n = 1.0f / 65536.0f;
    float mu = sums[ch] * inv_n;
    float var = fmaf(-mu, mu, sqs[ch] * inv_n);
    float is = 1.0f / sqrtf(var + 1e-5f);
    float aa = g[ch] * is;
    a[ch] = aa;
    c[ch] = fmaf(-mu, aa, bias[ch]);
}

// out = relu(a2[c]*y2 + c2[c]) in place (fp32, 4 elems/thread)
__global__ __launch_bounds__(256) void apply_kernel(
    float* __restrict__ y2, const float* __restrict__ a, const float* __restrict__ c)
{
    const size_t i = ((size_t)blockIdx.x * 256 + threadIdx.x) * 4;
    const int ch = (int)(i & 255);
    float4 v = *(const float4*)(y2 + i);
    const float4 av = *(const float4*)(a + ch);
    const float4 cv = *(const float4*)(c + ch);
    v.x = fmaxf(fmaf(v.x, av.x, cv.x), 0.0f);
    v.y = fmaxf(fmaf(v.y, av.y, cv.y), 0.0f);
    v.z = fmaxf(fmaf(v.z, av.z, cv.z), 0.0f);
    v.w = fmaxf(fmaf(v.w, av.w, cv.w), 0.0f);
    *(float4*)(y2 + i) = v;
}

extern "C" void kernel_launch(void* const* d_in, const int* in_sizes, int n_in,
                              void* d_out, int out_size, void* d_ws, size_t ws_size,
                              hipStream_t stream)
{
    const float* xyz1    = (const float*)d_in[0];
    const float* xyz2    = (const float*)d_in[1];
    const float* points1 = (const float*)d_in[2];
    const float* points2 = (const float*)d_in[3];
    const float* w1      = (const float*)d_in[4];
    const float* g1      = (const float*)d_in[5];
    const float* b1      = (const float*)d_in[6];
    const float* w2      = (const float*)d_in[7];
    const float* g2      = (const float*)d_in[8];
    const float* b2      = (const float*)d_in[9];
    float* out = (float*)d_out;

    char* ws = (char*)d_ws;
    float* sums1 = (float*)(ws + 0);
    float* sqs1  = (float*)(ws + 1024);
    float* a1    = (float*)(ws + 2048);
    float* c1    = (float*)(ws + 3072);
    float* sums2 = (float*)(ws + 4096);
    float* sqs2  = (float*)(ws + 5120);
    float* a2    = (float*)(ws + 6144);
    float* c2    = (float*)(ws + 7168);
    ushort_t* w1b = (ushort_t*)(ws + (64u << 10));    // 256 KB
    ushort_t* w2b = (ushort_t*)(ws + (320u << 10));   // 128 KB
    ushort_t* p2b = (ushort_t*)(ws + (1u << 20));     // 8.4 MB
    int*   idx   = (int*)(ws + (10u << 20));          // 768 KB
    float* wgt   = (float*)(ws + (11u << 20));        // 768 KB
    ushort_t* itp = (ushort_t*)(ws + (12u << 20));    // 32 MB
    ushort_t* y1  = (ushort_t*)(ws + (44u << 20));    // 32 MB (peak ~76 MB)

    hipMemsetAsync(ws, 0, 8192, stream);  // zero BN stat accumulators
    cvt_kernel<<<dim3(512), 256, 0, stream>>>(w1, w1b, 131072);
    cvt_kernel<<<dim3(256), 256, 0, stream>>>(w2, w2b, 65536);
    cvt4_kernel<<<dim3(4096), 256, 0, stream>>>(points2, p2b);
    knn_kernel<<<dim3(128, 16), 256, 0, stream>>>(xyz1, xyz2, idx, wgt);
    interp_kernel<<<dim3(2048), 256, 0, stream>>>(p2b, idx, wgt, itp);
    gemm1_kernel<<<dim3(2048), 256, 0, stream>>>(points1, itp, w1b, y1, sums1, sqs1);
    finalize_kernel<<<dim3(1), 256, 0, stream>>>(sums1, sqs1, g1, b1, a1, c1);
    gemm2_kernel<<<dim3(2048), 256, 0, stream>>>(y1, w2b, a1, c1, out, sums2, sqs2);
    finalize_kernel<<<dim3(1), 256, 0, stream>>>(sums2, sqs2, g2, b2, a2, c2);
    apply_kernel<<<dim3(16384), 256, 0, stream>>>(out, a2, c2);
}

// Round 6
// 286.139 us; speedup vs baseline: 1.2614x; 1.2614x over previous
//
#include <hip/hip_runtime.h>
#include <stdint.h>

typedef unsigned short ushort_t;
typedef __bf16 bf16x8 __attribute__((ext_vector_type(8)));
typedef float f32x4 __attribute__((ext_vector_type(4)));
typedef unsigned short ushort8 __attribute__((ext_vector_type(8)));
typedef unsigned short ushort4_t __attribute__((ext_vector_type(4)));

#define DEV static __device__ __forceinline__

DEV unsigned short f2bf(float f) {
    union { float f; unsigned int i; } v; v.f = f;
    unsigned int u = v.i;
    return (unsigned short)((u + 0x7fffu + ((u >> 16) & 1u)) >> 16);
}
DEV float bf2f(unsigned short u) {
    union { unsigned int i; float f; } v; v.i = ((unsigned int)u) << 16; return v.f;
}
DEV bf16x8 u2b(ushort8 u) { union { ushort8 u; bf16x8 b; } x; x.u = u; return x.b; }

// ---------------------------------------------------------------------------
// fp32 -> bf16 conversions
// ---------------------------------------------------------------------------
__global__ __launch_bounds__(256) void cvt_kernel(
    const float* __restrict__ in, ushort_t* __restrict__ out, int n)
{
    int i = blockIdx.x * 256 + threadIdx.x;
    if (i < n) out[i] = f2bf(in[i]);
}

__global__ __launch_bounds__(256) void cvt4_kernel(
    const float* __restrict__ in, ushort_t* __restrict__ out)
{
    int i = (blockIdx.x * 256 + threadIdx.x) * 4;
    float4 v = *(const float4*)(in + i);
    ushort4_t o;
    o[0] = f2bf(v.x); o[1] = f2bf(v.y); o[2] = f2bf(v.z); o[3] = f2bf(v.w);
    *(ushort4_t*)(out + i) = o;
}

// ---------------------------------------------------------------------------
// 3-NN: 8-way candidate split (round-5 version; left top-5). Stable ties.
// ---------------------------------------------------------------------------
__global__ __launch_bounds__(256) void knn_kernel(
    const float* __restrict__ xyz1, const float* __restrict__ xyz2,
    int* __restrict__ idx_out, float* __restrict__ w_out)
{
    __shared__ float4 P[1024];
    __shared__ float mD[24][32];
    __shared__ int   mI[24][32];
    const int b = blockIdx.y;
    const int tid = threadIdx.x;
    for (int s = tid; s < 1024; s += 256) {
        const float* p = xyz2 + ((size_t)b * 1024 + s) * 3;
        float x = p[0], y = p[1], z = p[2];
        float pp = __fadd_rn(__fadd_rn(__fmul_rn(x, x), __fmul_rn(y, y)), __fmul_rn(z, z));
        P[s] = make_float4(x, y, z, pp);
    }
    __syncthreads();
    const int ql = tid & 31;
    const int chunk = tid >> 5;
    const int n = blockIdx.x * 32 + ql;
    const float* q = xyz1 + ((size_t)b * 4096 + n) * 3;
    float qx = q[0], qy = q[1], qz = q[2];
    float qq = __fadd_rn(__fadd_rn(__fmul_rn(qx, qx), __fmul_rn(qy, qy)), __fmul_rn(qz, qz));
    float d0 = 1e30f, d1 = 1e30f, d2 = 1e30f;
    int i0 = 0, i1 = 0, i2 = 0;
    const int s0 = chunk * 128;
#pragma unroll 4
    for (int s = s0; s < s0 + 128; ++s) {
        float4 p = P[s];
        float dot = __fadd_rn(__fadd_rn(__fmul_rn(qx, p.x), __fmul_rn(qy, p.y)), __fmul_rn(qz, p.z));
        float d = __fsub_rn(__fadd_rn(qq, p.w), __fmul_rn(2.0f, dot));
        if (d < d2) {
            if (d < d1) {
                d2 = d1; i2 = i1;
                if (d < d0) { d1 = d0; i1 = i0; d0 = d; i0 = s; }
                else        { d1 = d;  i1 = s; }
            } else { d2 = d; i2 = s; }
        }
    }
    mD[chunk * 3 + 0][ql] = d0; mI[chunk * 3 + 0][ql] = i0;
    mD[chunk * 3 + 1][ql] = d1; mI[chunk * 3 + 1][ql] = i1;
    mD[chunk * 3 + 2][ql] = d2; mI[chunk * 3 + 2][ql] = i2;
    __syncthreads();
    if (tid < 32) {
        float e0 = 1e30f, e1 = 1e30f, e2 = 1e30f;
        int j0 = 0, j1 = 0, j2 = 0;
#pragma unroll
        for (int c = 0; c < 24; ++c) {
            float d = mD[c][ql]; int i = mI[c][ql];
            if (d < e2) {
                if (d < e1) {
                    e2 = e1; j2 = j1;
                    if (d < e0) { e1 = e0; j1 = j0; e0 = d; j0 = i; }
                    else        { e1 = d;  j1 = i; }
                } else { e2 = d; j2 = i; }
            }
        }
        float r0 = 1.0f / (e0 + 1e-8f);
        float r1 = 1.0f / (e1 + 1e-8f);
        float r2 = 1.0f / (e2 + 1e-8f);
        float rs = __fadd_rn(__fadd_rn(r0, r1), r2);
        size_t o = ((size_t)b * 4096 + n) * 3;
        idx_out[o + 0] = j0; idx_out[o + 1] = j1; idx_out[o + 2] = j2;
        w_out[o + 0] = r0 / rs; w_out[o + 1] = r1 / rs; w_out[o + 2] = r2 / rs;
    }
}

// ---------------------------------------------------------------------------
// Interp: itp[q][0:256] = sum_k w_k * p2b[idx_k] (bf16 gather from 8.4 MB)
// ---------------------------------------------------------------------------
__global__ __launch_bounds__(256) void interp_kernel(
    const ushort_t* __restrict__ p2b, const int* __restrict__ idx,
    const float* __restrict__ wgt, ushort_t* __restrict__ itp)
{
    const int t = blockIdx.x * 256 + threadIdx.x;
    const int q = t >> 3;
    const int cg = (t & 7) * 32;
    const size_t o = (size_t)q * 3;
    int i0 = idx[o], i1 = idx[o + 1], i2 = idx[o + 2];
    float w0 = wgt[o], w1 = wgt[o + 1], w2 = wgt[o + 2];
    const ushort_t* pb = p2b + (size_t)(q >> 12) * (1024 * 256);
    const ushort8* g0 = (const ushort8*)(pb + (size_t)i0 * 256 + cg);
    const ushort8* g1 = (const ushort8*)(pb + (size_t)i1 * 256 + cg);
    const ushort8* g2 = (const ushort8*)(pb + (size_t)i2 * 256 + cg);
    ushort8* dst = (ushort8*)(itp + (size_t)q * 256 + cg);
#pragma unroll
    for (int s = 0; s < 4; ++s) {
        ushort8 a = g0[s], b = g1[s], c = g2[s];
        ushort8 ov;
#pragma unroll
        for (int j = 0; j < 8; ++j) {
            float acc = __fmul_rn(w0, bf2f(a[j]));
            acc = fmaf(w1, bf2f(b[j]), acc);
            acc = fmaf(w2, bf2f(c[j]), acc);
            ov[j] = f2bf(acc);
        }
        dst[s] = ov;
    }
}

DEV void cvt8(const float4& u0, const float4& u1, ushort8& hv) {
    hv[0] = f2bf(u0.x); hv[1] = f2bf(u0.y); hv[2] = f2bf(u0.z); hv[3] = f2bf(u0.w);
    hv[4] = f2bf(u1.x); hv[5] = f2bf(u1.y); hv[6] = f2bf(u1.z); hv[7] = f2bf(u1.w);
}

// ---------------------------------------------------------------------------
// GEMM1 v4: barrier-free K-loop. Block = 512 thr (8 waves), BM=256, BN=128.
// B half (128 cols x 512 k) staged ONCE into LDS (row pad 520 -> conflict-free
// b128 frag reads). K-loop: A frags = direct global loads (p1 fp32+cvt for
// k<256, itp bf16 for k>=256; each wave-load consumes 16 full 64B lines),
// B frags from read-only LDS; both register-double-buffered; NO barriers.
// Twin blocks (bx&1 = N half) share the A panel via L2/L3.
// Epilogue: y1 bf16 + stats via LDS scratch (Bs dead) -> 1 atomic/col/block.
// ---------------------------------------------------------------------------
__global__ __launch_bounds__(512, 2) void gemm1_kernel(
    const float* __restrict__ p1, const ushort_t* __restrict__ itp,
    const ushort_t* __restrict__ w1b, ushort_t* __restrict__ y,
    float* __restrict__ sums, float* __restrict__ sqs)
{
    __shared__ __align__(16) char smem[133120];   // Bs: 128 x 520 ushort
    ushort_t* Bs = (ushort_t*)smem;
    const int tid = threadIdx.x;
    const int wave = tid >> 6, lane = tid & 63;
    const int frl = lane & 15, fq = lane >> 4;
    const int panel = blockIdx.x >> 1, nb = blockIdx.x & 1;
    const int m0 = panel * 256;

    // stage B once: 4 threads per col, 16 x 8-elem chunks each
    {
        const int c = tid >> 2, qq = tid & 3;
        const ushort_t* src = w1b + (size_t)(nb * 128 + c) * 512;
        ushort_t* dst = Bs + c * 520;
#pragma unroll
        for (int s = 0; s < 16; ++s) {
            int off = qq * 8 + s * 32;
            *(ushort8*)(dst + off) = *(const ushort8*)(src + off);
        }
    }

    f32x4 acc[2][8];
#pragma unroll
    for (int i = 0; i < 2; ++i)
#pragma unroll
        for (int j = 0; j < 8; ++j) acc[i][j] = f32x4{0.0f, 0.0f, 0.0f, 0.0f};

    __syncthreads();   // only barrier before K-loop

    const int row0 = m0 + wave * 32 + frl;
    bf16x8 afb[2][2], bfb[2][8];

#define G1_LOADA(buf, kc) {                                                        \
    if ((kc) < 8) {                                                                \
        _Pragma("unroll")                                                          \
        for (int i = 0; i < 2; ++i) {                                              \
            const float4* g = (const float4*)(p1 + (size_t)(row0 + i * 16) * 256   \
                                              + (kc) * 32 + fq * 8);               \
            float4 u0 = g[0], u1 = g[1];                                           \
            ushort8 hv; cvt8(u0, u1, hv);                                          \
            buf[i] = u2b(hv);                                                      \
        }                                                                          \
    } else {                                                                       \
        _Pragma("unroll")                                                          \
        for (int i = 0; i < 2; ++i)                                                \
            buf[i] = *(const bf16x8*)(itp + (size_t)(row0 + i * 16) * 256          \
                                      + ((kc) - 8) * 32 + fq * 8);                 \
    } }
#define G1_LOADB(buf, kc) { _Pragma("unroll")                                      \
    for (int j = 0; j < 8; ++j)                                                    \
        buf[j] = *(const bf16x8*)(Bs + (j * 16 + frl) * 520 + (kc) * 32 + fq * 8); }

    G1_LOADA(afb[0], 0); G1_LOADB(bfb[0], 0);
#pragma unroll
    for (int kc = 0; kc < 16; ++kc) {
        const int cur = kc & 1, nxt = cur ^ 1;
        if (kc < 15) { G1_LOADA(afb[nxt], kc + 1); G1_LOADB(bfb[nxt], kc + 1); }
#pragma unroll
        for (int i = 0; i < 2; ++i)
#pragma unroll
            for (int j = 0; j < 8; ++j)
                acc[i][j] = __builtin_amdgcn_mfma_f32_16x16x32_bf16(afb[cur][i], bfb[cur][j], acc[i][j], 0, 0, 0);
    }

    // epilogue: y1 store + per-col stats
    float ps[8], pq[8];
#pragma unroll
    for (int j = 0; j < 8; ++j) {
        const int colg = nb * 128 + j * 16 + frl;
        float s = 0.f, q = 0.f;
#pragma unroll
        for (int i = 0; i < 2; ++i)
#pragma unroll
            for (int rr = 0; rr < 4; ++rr) {
                ushort_t hb = f2bf(acc[i][j][rr]);
                float v = bf2f(hb);
                y[(size_t)(m0 + wave * 32 + i * 16 + fq * 4 + rr) * 256 + colg] = hb;
                s += v; q = fmaf(v, v, q);
            }
        s += __shfl_xor(s, 16); s += __shfl_xor(s, 32);
        q += __shfl_xor(q, 16); q += __shfl_xor(q, 32);
        ps[j] = s; pq[j] = q;
    }
    __syncthreads();                      // Bs now dead -> reuse as scratch
    float* scrS = (float*)smem;           // [8][128]
    float* scrQ = (float*)(smem + 4096);  // [8][128]
    if (fq == 0) {
#pragma unroll
        for (int j = 0; j < 8; ++j) {
            scrS[wave * 128 + j * 16 + frl] = ps[j];
            scrQ[wave * 128 + j * 16 + frl] = pq[j];
        }
    }
    __syncthreads();
    if (tid < 128) {
        float s = 0.f, q = 0.f;
#pragma unroll
        for (int w = 0; w < 8; ++w) { s += scrS[w * 128 + tid]; q += scrQ[w * 128 + tid]; }
        atomicAdd(&sums[nb * 128 + tid], s);
        atomicAdd(&sqs[nb * 128 + tid], q);
    }
}

// ---------------------------------------------------------------------------
// GEMM2 v4: y2(bf16) = relu(bn1(y1)) @ w2^T. Block 512 thr, BM=128, BN=128.
// A (BN folded at stage time) AND B staged once in LDS (264 pad); K-loop has
// zero barriers. Wave w: rows (w&3)*32 (2 bands), cols (w>>2)*64 (4 bands).
// ---------------------------------------------------------------------------
__global__ __launch_bounds__(512, 2) void gemm2_kernel(
    const ushort_t* __restrict__ y1, const ushort_t* __restrict__ w2b,
    const float* __restrict__ a1, const float* __restrict__ c1,
    ushort_t* __restrict__ y2, float* __restrict__ sums, float* __restrict__ sqs)
{
    __shared__ __align__(16) char smem[137216];
    ushort_t* As = (ushort_t*)smem;                  // 128 x 264
    ushort_t* Bs = (ushort_t*)(smem + 67584);        // 128 x 264
    float* sAv = (float*)(smem + 135168);            // 256 f
    float* sCv = (float*)(smem + 136192);            // 256 f
    const int tid = threadIdx.x;
    const int wave = tid >> 6, lane = tid & 63;
    const int frl = lane & 15, fq = lane >> 4;
    const int panel = blockIdx.x >> 1, nb = blockIdx.x & 1;
    const int m0 = panel * 128;

    if (tid < 256) { sAv[tid] = a1[tid]; sCv[tid] = c1[tid]; }
    __syncthreads();

    // stage A (BN+relu folded) and B
    {
        const int r = tid >> 2, qq = tid & 3;
        const ushort_t* srcA = y1 + (size_t)(m0 + r) * 256;
        ushort_t* dstA = As + r * 264;
        const ushort_t* srcB = w2b + (size_t)(nb * 128 + r) * 256;
        ushort_t* dstB = Bs + r * 264;
#pragma unroll
        for (int s = 0; s < 8; ++s) {
            int off = qq * 8 + s * 32;
            ushort8 raw = *(const ushort8*)(srcA + off);
            ushort8 hv;
#pragma unroll
            for (int e = 0; e < 8; ++e) {
                float v = bf2f(raw[e]);
                hv[e] = f2bf(fmaxf(fmaf(v, sAv[off + e], sCv[off + e]), 0.0f));
            }
            *(ushort8*)(dstA + off) = hv;
            *(ushort8*)(dstB + off) = *(const ushort8*)(srcB + off);
        }
    }

    f32x4 acc[2][4];
#pragma unroll
    for (int i = 0; i < 2; ++i)
#pragma unroll
        for (int j = 0; j < 4; ++j) acc[i][j] = f32x4{0.0f, 0.0f, 0.0f, 0.0f};

    __syncthreads();

    const int rg = (wave & 3) * 32, cg = (wave >> 2) * 64;
    bf16x8 afb[2][2], bfb[2][4];

#define G2_LOADA(buf, kc) { _Pragma("unroll")                                      \
    for (int i = 0; i < 2; ++i)                                                    \
        buf[i] = *(const bf16x8*)(As + (rg + i * 16 + frl) * 264 + (kc) * 32 + fq * 8); }
#define G2_LOADB(buf, kc) { _Pragma("unroll")                                      \
    for (int j = 0; j < 4; ++j)                                                    \
        buf[j] = *(const bf16x8*)(Bs + (cg + j * 16 + frl) * 264 + (kc) * 32 + fq * 8); }

    G2_LOADA(afb[0], 0); G2_LOADB(bfb[0], 0);
#pragma unroll
    for (int kc = 0; kc < 8; ++kc) {
        const int cur = kc & 1, nxt = cur ^ 1;
        if (kc < 7) { G2_LOADA(afb[nxt], kc + 1); G2_LOADB(bfb[nxt], kc + 1); }
#pragma unroll
        for (int i = 0; i < 2; ++i)
#pragma unroll
            for (int j = 0; j < 4; ++j)
                acc[i][j] = __builtin_amdgcn_mfma_f32_16x16x32_bf16(afb[cur][i], bfb[cur][j], acc[i][j], 0, 0, 0);
    }

    float ps[4], pq[4];
#pragma unroll
    for (int j = 0; j < 4; ++j) {
        const int colg = nb * 128 + cg + j * 16 + frl;
        float s = 0.f, q = 0.f;
#pragma unroll
        for (int i = 0; i < 2; ++i)
#pragma unroll
            for (int rr = 0; rr < 4; ++rr) {
                ushort_t hb = f2bf(acc[i][j][rr]);
                float v = bf2f(hb);
                y2[(size_t)(m0 + rg + i * 16 + fq * 4 + rr) * 256 + colg] = hb;
                s += v; q = fmaf(v, v, q);
            }
        s += __shfl_xor(s, 16); s += __shfl_xor(s, 32);
        q += __shfl_xor(q, 16); q += __shfl_xor(q, 32);
        ps[j] = s; pq[j] = q;
    }
    __syncthreads();                      // As/Bs dead -> scratch
    float* scrS = (float*)smem;           // [8][64]
    float* scrQ = (float*)(smem + 2048);  // [8][64]
    if (fq == 0) {
#pragma unroll
        for (int j = 0; j < 4; ++j) {
            scrS[wave * 64 + j * 16 + frl] = ps[j];
            scrQ[wave * 64 + j * 16 + frl] = pq[j];
        }
    }
    __syncthreads();
    if (tid < 128) {
        const int g = tid >> 6, cw = tid & 63;
        float s = 0.f, q = 0.f;
#pragma unroll
        for (int k = 0; k < 4; ++k) {
            s += scrS[(g * 4 + k) * 64 + cw];
            q += scrQ[(g * 4 + k) * 64 + cw];
        }
        atomicAdd(&sums[nb * 128 + g * 64 + cw], s);
        atomicAdd(&sqs[nb * 128 + g * 64 + cw], q);
    }
}

__global__ __launch_bounds__(256) void finalize_kernel(
    const float* __restrict__ sums, const float* __restrict__ sqs,
    const float* __restrict__ g, const float* __restrict__ bias,
    float* __restrict__ a, float* __restrict__ c)
{
    const int ch = threadIdx.x;
    const float inv_n = 1.0f / 65536.0f;
    float mu = sums[ch] * inv_n;
    float var = fmaf(-mu, mu, sqs[ch] * inv_n);
    float is = 1.0f / sqrtf(var + 1e-5f);
    float aa = g[ch] * is;
    a[ch] = aa;
    c[ch] = fmaf(-mu, aa, bias[ch]);
}

// out(fp32) = relu(a2[c]*y2b + c2[c]); 8 elems/thread
__global__ __launch_bounds__(256) void apply_kernel(
    const ushort_t* __restrict__ y2, const float* __restrict__ a,
    const float* __restrict__ c, float* __restrict__ out)
{
    const size_t i = ((size_t)blockIdx.x * 256 + threadIdx.x) * 8;
    const int ch = (int)(i & 255);
    ushort8 raw = *(const ushort8*)(y2 + i);
    float4 o0, o1;
    const float4 a0 = *(const float4*)(a + ch), a1v = *(const float4*)(a + ch + 4);
    const float4 c0 = *(const float4*)(c + ch), c1v = *(const float4*)(c + ch + 4);
    o0.x = fmaxf(fmaf(bf2f(raw[0]), a0.x, c0.x), 0.0f);
    o0.y = fmaxf(fmaf(bf2f(raw[1]), a0.y, c0.y), 0.0f);
    o0.z = fmaxf(fmaf(bf2f(raw[2]), a0.z, c0.z), 0.0f);
    o0.w = fmaxf(fmaf(bf2f(raw[3]), a0.w, c0.w), 0.0f);
    o1.x = fmaxf(fmaf(bf2f(raw[4]), a1v.x, c1v.x), 0.0f);
    o1.y = fmaxf(fmaf(bf2f(raw[5]), a1v.y, c1v.y), 0.0f);
    o1.z = fmaxf(fmaf(bf2f(raw[6]), a1v.z, c1v.z), 0.0f);
    o1.w = fmaxf(fmaf(bf2f(raw[7]), a1v.w, c1v.w), 0.0f);
    *(float4*)(out + i) = o0;
    *(float4*)(out + i + 4) = o1;
}

extern "C" void kernel_launch(void* const* d_in, const int* in_sizes, int n_in,
                              void* d_out, int out_size, void* d_ws, size_t ws_size,
                              hipStream_t stream)
{
    const float* xyz1    = (const float*)d_in[0];
    const float* xyz2    = (const float*)d_in[1];
    const float* points1 = (const float*)d_in[2];
    const float* points2 = (const float*)d_in[3];
    const float* w1      = (const float*)d_in[4];
    const float* g1      = (const float*)d_in[5];
    const float* b1      = (const float*)d_in[6];
    const float* w2      = (const float*)d_in[7];
    const float* g2      = (const float*)d_in[8];
    const float* b2      = (const float*)d_in[9];
    float* out = (float*)d_out;

    char* ws = (char*)d_ws;
    float* sums1 = (float*)(ws + 0);
    float* sqs1  = (float*)(ws + 1024);
    float* a1    = (float*)(ws + 2048);
    float* c1    = (float*)(ws + 3072);
    float* sums2 = (float*)(ws + 4096);
    float* sqs2  = (float*)(ws + 5120);
    float* a2    = (float*)(ws + 6144);
    float* c2    = (float*)(ws + 7168);
    ushort_t* w1b = (ushort_t*)(ws + (64u << 10));    // 256 KB
    ushort_t* w2b = (ushort_t*)(ws + (320u << 10));   // 128 KB
    ushort_t* p2b = (ushort_t*)(ws + (1u << 20));     // 8.4 MB
    int*   idx   = (int*)(ws + (10u << 20));          // 768 KB
    float* wgt   = (float*)(ws + (11u << 20));        // 768 KB
    ushort_t* itp = (ushort_t*)(ws + (12u << 20));    // 32 MB
    ushort_t* y1  = (ushort_t*)(ws + (44u << 20));    // 32 MB (peak ~76 MB)
    ushort_t* y2b = itp;   // itp dead after gemm1; reuse for y2 (bf16)

    hipMemsetAsync(ws, 0, 8192, stream);  // zero BN stat accumulators
    cvt_kernel<<<dim3(512), 256, 0, stream>>>(w1, w1b, 131072);
    cvt_kernel<<<dim3(256), 256, 0, stream>>>(w2, w2b, 65536);
    cvt4_kernel<<<dim3(4096), 256, 0, stream>>>(points2, p2b);
    knn_kernel<<<dim3(128, 16), 256, 0, stream>>>(xyz1, xyz2, idx, wgt);
    interp_kernel<<<dim3(2048), 256, 0, stream>>>(p2b, idx, wgt, itp);
    gemm1_kernel<<<dim3(512), 512, 0, stream>>>(points1, itp, w1b, y1, sums1, sqs1);
    finalize_kernel<<<dim3(1), 256, 0, stream>>>(sums1, sqs1, g1, b1, a1, c1);
    gemm2_kernel<<<dim3(1024), 512, 0, stream>>>(y1, w2b, a1, c1, y2b, sums2, sqs2);
    finalize_kernel<<<dim3(1), 256, 0, stream>>>(sums2, sqs2, g2, b2, a2, c2);
    apply_kernel<<<dim3(8192), 256, 0, stream>>>(y2b, a2, c2, out);
}